// Round 3
// baseline (546.460 us; speedup 1.0000x reference)
//
#include <hip/hip_runtime.h>
#include <cstdint>
#include <cstddef>

#define LN_EPS 1e-5f

typedef short bf16x8 __attribute__((ext_vector_type(8)));
typedef float f32x4 __attribute__((ext_vector_type(4)));

__device__ __forceinline__ uint16_t f2bf(float f){
  uint32_t u = __float_as_uint(f);
  u += 0x7fffu + ((u >> 16) & 1u);
  return (uint16_t)(u >> 16);
}
__device__ __forceinline__ float bf2f(uint16_t h){
  return __uint_as_float(((uint32_t)h) << 16);
}
__device__ __forceinline__ float sigm(float x){
  return __builtin_amdgcn_rcpf(1.0f + __expf(-x));
}

// ---------------- K0: convert 6 weight matrices (128x128 fp32) to bf16 ----------------
// order: 0=left_proj_w 1=left_gate_w 2=right_proj_w 3=right_gate_w 4=gating_w 5=out_proj_w
__global__ __launch_bounds__(256) void wconv_k(
    const float* __restrict__ w0, const float* __restrict__ w1,
    const float* __restrict__ w2, const float* __restrict__ w3,
    const float* __restrict__ w4, const float* __restrict__ w5,
    uint16_t* __restrict__ dst)
{
  int i = blockIdx.x*256 + threadIdx.x;   // 6*16384 total
  int m = i >> 14, e = i & 16383;
  const float* s = (m==0)?w0:(m==1)?w1:(m==2)?w2:(m==3)?w3:(m==4)?w4:w5;
  dst[i] = f2bf(s[e]);
}

// ---------------- K1: LN + 5 projections, A-in-registers ----------------
// 4096 blocks x 256 threads; block owns 64 positions. Each wave owns 16 rows x all 128 cols.
// A-fragments live in 16 VGPRs per lane -> gemm passes touch no LDS, no barriers inside.
// outputs: leftT/rightT/gbuf ALL c-major [C][N*N] bf16 (transposed via 16KB LDS buffer).
__global__ __launch_bounds__(256) void k1_proj(
    const float* __restrict__ act, const float* __restrict__ mask,
    const float* __restrict__ lnw, const float* __restrict__ lnb,
    const float* __restrict__ lpb, const float* __restrict__ lgB,
    const float* __restrict__ rpb, const float* __restrict__ rgB,
    const float* __restrict__ gB,
    const uint16_t* __restrict__ wbf,
    uint16_t* __restrict__ leftT, uint16_t* __restrict__ rightT,
    uint16_t* __restrict__ gbuf)
{
  __shared__ uint16_t sA[64*128];   // 16KB; phase A: [row64][c128]; epilogues: [c128][p64]
  __shared__ float sMask[64];
  const int t = threadIdx.x;
  const int p0 = blockIdx.x * 64;

  { // ---- LayerNorm (fp32), 4 threads per row ----
    const int row = t >> 2, q = t & 3;
    const float* src = act + (size_t)(p0 + row)*128 + q*32;
    float x[32];
#pragma unroll
    for(int u=0;u<8;u++){
      float4 v = *(const float4*)(src + u*4);
      x[u*4+0]=v.x; x[u*4+1]=v.y; x[u*4+2]=v.z; x[u*4+3]=v.w;
    }
    float s=0.f, s2=0.f;
#pragma unroll
    for(int u=0;u<32;u++){ s += x[u]; s2 += x[u]*x[u]; }
    s  += __shfl_xor(s,1);  s  += __shfl_xor(s,2);
    s2 += __shfl_xor(s2,1); s2 += __shfl_xor(s2,2);
    const float mu   = s * (1.f/128.f);
    const float var  = s2 * (1.f/128.f) - mu*mu;
    const float rstd = rsqrtf(var + LN_EPS);
    const int rs = (row&7)<<4;
#pragma unroll
    for(int u=0;u<4;u++){
      const int c0 = q*32 + u*8;
      float4 w0 = *(const float4*)(lnw + c0), w1 = *(const float4*)(lnw + c0 + 4);
      float4 b0 = *(const float4*)(lnb + c0), b1 = *(const float4*)(lnb + c0 + 4);
      uint16_t h[8];
      h[0]=f2bf((x[u*8+0]-mu)*rstd*w0.x+b0.x); h[1]=f2bf((x[u*8+1]-mu)*rstd*w0.y+b0.y);
      h[2]=f2bf((x[u*8+2]-mu)*rstd*w0.z+b0.z); h[3]=f2bf((x[u*8+3]-mu)*rstd*w0.w+b0.w);
      h[4]=f2bf((x[u*8+4]-mu)*rstd*w1.x+b1.x); h[5]=f2bf((x[u*8+5]-mu)*rstd*w1.y+b1.y);
      h[6]=f2bf((x[u*8+6]-mu)*rstd*w1.z+b1.z); h[7]=f2bf((x[u*8+7]-mu)*rstd*w1.w+b1.w);
      uint4 pk;
      pk.x = (uint32_t)h[0] | ((uint32_t)h[1]<<16);
      pk.y = (uint32_t)h[2] | ((uint32_t)h[3]<<16);
      pk.z = (uint32_t)h[4] | ((uint32_t)h[5]<<16);
      pk.w = (uint32_t)h[6] | ((uint32_t)h[7]<<16);
      *(uint4*)((char*)sA + row*256 + ((c0*2) ^ rs)) = pk;
    }
    if(t < 64) sMask[t] = mask[p0 + t];
  }
  __syncthreads();                                       // bar1

  const int lane = t & 63, wid = t >> 6;
  const int l15 = lane & 15, lh = lane >> 4;
  const f32x4 z4 = {0.f,0.f,0.f,0.f};

  // ---- load this wave's A-slice into registers (16 VGPRs) ----
  bf16x8 af[4];
  {
    const int row = wid*16 + l15;
    const int rs = (row&7)<<4;
#pragma unroll
    for(int ks=0;ks<4;ks++)
      af[ks] = *(const bf16x8*)((const char*)sA + row*256 + ((ks*64 + lh*16) ^ rs));
  }
  __syncthreads();                                       // bar2: sA free for reuse

  f32x4 aP[8], aG[8];

  auto gemm2 = [&](const uint16_t* __restrict__ W0, const uint16_t* __restrict__ W1){
#pragma unroll
    for(int ks=0;ks<4;ks++){
#pragma unroll
      for(int tn=0;tn<8;tn++){
        const int o = tn*16 + l15;
        const bf16x8 b0 = *(const bf16x8*)(W0 + o*128 + ks*32 + lh*8);
        const bf16x8 b1 = *(const bf16x8*)(W1 + o*128 + ks*32 + lh*8);
        aP[tn] = __builtin_amdgcn_mfma_f32_16x16x32_bf16(af[ks], b0, aP[tn], 0,0,0);
        aG[tn] = __builtin_amdgcn_mfma_f32_16x16x32_bf16(af[ks], b1, aG[tn], 0,0,0);
      }
    }
  };
  auto gemm1 = [&](const uint16_t* __restrict__ W0){
#pragma unroll
    for(int ks=0;ks<4;ks++){
#pragma unroll
      for(int tn=0;tn<8;tn++){
        const int o = tn*16 + l15;
        const bf16x8 b0 = *(const bf16x8*)(W0 + o*128 + ks*32 + lh*8);
        aP[tn] = __builtin_amdgcn_mfma_f32_16x16x32_bf16(af[ks], b0, aP[tn], 0,0,0);
      }
    }
  };

  // write combined values into sA viewed as [c 128][p 64] (128B rows), swizzle bits 4..6
  const int prow = wid*16 + lh*4;               // base p of this lane's 4 acc rows
  const int poff = wid*32 + lh*8;               // byte offset of those 4 bf16 within a c-row

  auto epi_write = [&](const float* __restrict__ pb, const float* __restrict__ gb2){
#pragma unroll
    for(int tn=0;tn<8;tn++){
      const int c = tn*16 + l15;
      const float pbv = pb[c], gbv = gb2[c];
      uint16_t h[4];
#pragma unroll
      for(int r=0;r<4;r++)
        h[r] = f2bf(sMask[prow+r]*(aP[tn][r] + pbv) * sigm(aG[tn][r] + gbv));
      uint2 pk;
      pk.x = (uint32_t)h[0] | ((uint32_t)h[1]<<16);
      pk.y = (uint32_t)h[2] | ((uint32_t)h[3]<<16);
      *(uint2*)((char*)sA + c*128 + (poff ^ ((c&7)<<4))) = pk;
    }
  };
  auto epi_readout = [&](uint16_t* __restrict__ dstT){
    const int c = t >> 1, ph = (t & 1)*32;
    const int cs = (c&7)<<4;
    uint4 q[4];
#pragma unroll
    for(int u=0;u<4;u++)
      q[u] = *(const uint4*)((const char*)sA + c*128 + ((ph*2 + u*16) ^ cs));
    uint16_t* dst = dstT + (size_t)c*262144 + p0 + ph;
    *(uint4*)(dst+ 0)=q[0]; *(uint4*)(dst+ 8)=q[1];
    *(uint4*)(dst+16)=q[2]; *(uint4*)(dst+24)=q[3];
  };

  // ---- left ----
#pragma unroll
  for(int a=0;a<8;a++){ aP[a]=z4; aG[a]=z4; }
  gemm2(wbf + 0*16384, wbf + 1*16384);
  epi_write(lpb, lgB);
  __syncthreads();                                       // bar3
  epi_readout(leftT);

  // ---- right ----
#pragma unroll
  for(int a=0;a<8;a++){ aP[a]=z4; aG[a]=z4; }
  gemm2(wbf + 2*16384, wbf + 3*16384);
  __syncthreads();                                       // bar4: readout-L complete
  epi_write(rpb, rgB);
  __syncthreads();                                       // bar5
  epi_readout(rightT);

  // ---- gating (sigmoid only) ----
#pragma unroll
  for(int a=0;a<8;a++) aP[a]=z4;
  gemm1(wbf + 4*16384);
  __syncthreads();                                       // bar6: readout-R complete
#pragma unroll
  for(int tn=0;tn<8;tn++){
    const int c = tn*16 + l15;
    const float gbv = gB[c];
    uint16_t h[4];
#pragma unroll
    for(int r=0;r<4;r++)
      h[r] = f2bf(sigm(aP[tn][r] + gbv));
    uint2 pk;
    pk.x = (uint32_t)h[0] | ((uint32_t)h[1]<<16);
    pk.y = (uint32_t)h[2] | ((uint32_t)h[3]<<16);
    *(uint2*)((char*)sA + c*128 + (poff ^ ((c&7)<<4))) = pk;
  }
  __syncthreads();                                       // bar7
  epi_readout(gbuf);
}

// ---------------- K2: triangle einsum, 128 c-batched 512x512x512 GEMMs ----------------
// t_c[i][j] = sum_k L_c[i][k] * R_c[j][k]; 2048 blocks (XCD-chunk swizzled), tile 128x128, BK=64.
__global__ __launch_bounds__(256) void k2_tri(
    const uint16_t* __restrict__ leftT, const uint16_t* __restrict__ rightT,
    uint16_t* __restrict__ tbuf)
{
  __shared__ uint16_t sm[2*128*64];   // 32KB: sL | sR; reused as [128][128] C-tile in epilogue
  uint16_t* sL = sm;
  uint16_t* sR = sm + 128*64;
  // XCD-chunked bijective swizzle: 2048 = 8 * 256 -> each XCD gets 16 consecutive c-groups
  const int bx = (blockIdx.x & 7)*256 + (blockIdx.x >> 3);
  const int c = bx >> 4, it = (bx >> 2) & 3, jt = bx & 3;
  const uint16_t* L = leftT  + (size_t)c*262144;
  const uint16_t* R = rightT + (size_t)c*262144;
  const int t = threadIdx.x, lane = t & 63, wid = t >> 6;
  const int wm = wid >> 1, wn = wid & 1;   // wave: 64x64 of the 128x128 tile
  const int l15 = lane & 15, lh = lane >> 4;
  const f32x4 z4 = {0.f,0.f,0.f,0.f};
  f32x4 acc[4][4];
#pragma unroll
  for(int a=0;a<4;a++) for(int b=0;b<4;b++) acc[a][b]=z4;

  const int srow = t >> 1, shalf = (t & 1)*64;  // staging: 64B per thread per matrix
  for(int kt=0; kt<8; kt++){
    __syncthreads();
#pragma unroll
    for(int u=0;u<4;u++){
      const int kb = shalf + u*16;                 // byte within the 128B row
      const int ge = kt*64 + (kb >> 1);            // global k element
      const int db = srow*128 + (kb ^ ((srow&7)<<4));
      uint4 va = *(const uint4*)(L + (size_t)(it*128+srow)*512 + ge);
      *(uint4*)((char*)sL + db) = va;
      uint4 vb = *(const uint4*)(R + (size_t)(jt*128+srow)*512 + ge);
      *(uint4*)((char*)sR + db) = vb;
    }
    __syncthreads();
#pragma unroll
    for(int ks=0;ks<2;ks++){
      bf16x8 af[4], bv[4];
#pragma unroll
      for(int tm=0;tm<4;tm++){
        const int row = wm*64 + tm*16 + l15;
        const int byte = row*128 + ((ks*64 + lh*16) ^ ((row&7)<<4));
        af[tm] = *(const bf16x8*)((const char*)sL + byte);
      }
#pragma unroll
      for(int tn=0;tn<4;tn++){
        const int row = wn*64 + tn*16 + l15;
        const int byte = row*128 + ((ks*64 + lh*16) ^ ((row&7)<<4));
        bv[tn] = *(const bf16x8*)((const char*)sR + byte);
      }
#pragma unroll
      for(int tm=0;tm<4;tm++)
#pragma unroll
        for(int tn=0;tn<4;tn++)
          acc[tm][tn] = __builtin_amdgcn_mfma_f32_16x16x32_bf16(af[tm], bv[tn], acc[tm][tn], 0,0,0);
    }
  }
  // epilogue: scatter into LDS [i][j] tile, then coalesced 128B-contiguous stores
  __syncthreads();
#pragma unroll
  for(int tm=0;tm<4;tm++){
#pragma unroll
    for(int tn=0;tn<4;tn++){
      const int j = wn*64 + tn*16 + l15;
#pragma unroll
      for(int r=0;r<4;r++){
        const int i = wm*64 + tm*16 + lh*4 + r;
        const int byte = i*256 + ((j*2) ^ ((i&7)<<4));
        *(uint16_t*)((char*)sm + byte) = f2bf(acc[tm][tn][r]);
      }
    }
  }
  __syncthreads();
  {
    const int i = t >> 1, half = (t & 1)*64;
    uint16_t* dst = tbuf + (size_t)c*262144 + (size_t)(it*128+i)*512 + jt*128 + half;
#pragma unroll
    for(int u=0;u<8;u++){
      const int byte = i*256 + ((half*2 + u*16) ^ ((i&7)<<4));
      *(uint4*)(dst + u*8) = *(const uint4*)((const char*)sm + byte);
    }
  }
}

// ---------------- K3: LN_c + out_proj + gating multiply ----------------
// grid 4096: block owns positions (i, j0..j0+63); reads t and g (both c-major), writes fp32 out.
__global__ __launch_bounds__(256) void k3_out(
    const uint16_t* __restrict__ tbuf, const uint16_t* __restrict__ gbuf,
    const float* __restrict__ lncw, const float* __restrict__ lncb,
    const uint16_t* __restrict__ wbf, const float* __restrict__ opb,
    float* __restrict__ out)
{
  __shared__ uint16_t sT2[64*128];  // 16KB [p 64][c 128] bf16, swizzled
  __shared__ uint16_t sG[64*128];   // 16KB [p 64][c 128] bf16, swizzled
  const int bx = blockIdx.x;
  const int i = bx >> 3, j0 = (bx & 7)*64;
  const int t = threadIdx.x;
  const int pbase = i*512 + j0;

  { // transpose-load t and g: thread -> (c = t>>1, 32 consecutive j)
    const int c = t >> 1, ph = (t & 1)*32;
    const uint16_t* srcT = tbuf + (size_t)c*262144 + pbase + ph;
    const uint16_t* srcG = gbuf + (size_t)c*262144 + pbase + ph;
#pragma unroll
    for(int u=0;u<4;u++){
      uint4 v = *(const uint4*)(srcT + u*8);
      uint4 g = *(const uint4*)(srcG + u*8);
      uint16_t et[8], eg[8];
      et[0]=(uint16_t)(v.x&0xffff); et[1]=(uint16_t)(v.x>>16);
      et[2]=(uint16_t)(v.y&0xffff); et[3]=(uint16_t)(v.y>>16);
      et[4]=(uint16_t)(v.z&0xffff); et[5]=(uint16_t)(v.z>>16);
      et[6]=(uint16_t)(v.w&0xffff); et[7]=(uint16_t)(v.w>>16);
      eg[0]=(uint16_t)(g.x&0xffff); eg[1]=(uint16_t)(g.x>>16);
      eg[2]=(uint16_t)(g.y&0xffff); eg[3]=(uint16_t)(g.y>>16);
      eg[4]=(uint16_t)(g.z&0xffff); eg[5]=(uint16_t)(g.z>>16);
      eg[6]=(uint16_t)(g.w&0xffff); eg[7]=(uint16_t)(g.w>>16);
#pragma unroll
      for(int k2=0;k2<8;k2++){
        const int p = ph + u*8 + k2;
        const int byte = p*256 + ((c*2) ^ ((p&7)<<4));
        *(uint16_t*)((char*)sT2 + byte) = et[k2];
        *(uint16_t*)((char*)sG + byte) = eg[k2];
      }
    }
  }
  __syncthreads();

  const int lane = t & 63, wid = t >> 6;
  { // LayerNorm over c per position row (fp32), 4 lanes per row
    const int row = wid*16 + (lane & 15);
    const int q = lane >> 4;
    float xs[32];
#pragma unroll
    for(int u=0;u<4;u++){
      const int kb = q*64 + u*16;
      const int byte = row*256 + (kb ^ ((row&7)<<4));
      uint4 v = *(const uint4*)((const char*)sT2 + byte);
      xs[u*8+0]=bf2f((uint16_t)(v.x&0xffff)); xs[u*8+1]=bf2f((uint16_t)(v.x>>16));
      xs[u*8+2]=bf2f((uint16_t)(v.y&0xffff)); xs[u*8+3]=bf2f((uint16_t)(v.y>>16));
      xs[u*8+4]=bf2f((uint16_t)(v.z&0xffff)); xs[u*8+5]=bf2f((uint16_t)(v.z>>16));
      xs[u*8+6]=bf2f((uint16_t)(v.w&0xffff)); xs[u*8+7]=bf2f((uint16_t)(v.w>>16));
    }
    float s=0.f, s2=0.f;
#pragma unroll
    for(int u=0;u<32;u++){ s += xs[u]; s2 += xs[u]*xs[u]; }
    s  += __shfl_xor(s,16);  s  += __shfl_xor(s,32);
    s2 += __shfl_xor(s2,16); s2 += __shfl_xor(s2,32);
    const float mu   = s * (1.f/128.f);
    const float var  = s2 * (1.f/128.f) - mu*mu;
    const float rstd = rsqrtf(var + LN_EPS);
#pragma unroll
    for(int u=0;u<4;u++){
      const int kb = q*64 + u*16;
      const int c0 = (kb ^ ((row&7)<<4)) >> 1;    // de-swizzled channel of this 16B block
      uint16_t h[8];
#pragma unroll
      for(int j=0;j<8;j++)
        h[j] = f2bf((xs[u*8+j]-mu)*rstd*lncw[c0+j] + lncb[c0+j]);
      uint4 pk;
      pk.x = (uint32_t)h[0] | ((uint32_t)h[1]<<16);
      pk.y = (uint32_t)h[2] | ((uint32_t)h[3]<<16);
      pk.z = (uint32_t)h[4] | ((uint32_t)h[5]<<16);
      pk.w = (uint32_t)h[6] | ((uint32_t)h[7]<<16);
      const int byte = row*256 + (kb ^ ((row&7)<<4));
      *(uint4*)((char*)sT2 + byte) = pk;
    }
  }
  __syncthreads();

  const int wm = wid >> 1, wn = wid & 1;
  const int l15 = lane & 15, lh = lane >> 4;
  const f32x4 z4 = {0.f,0.f,0.f,0.f};
  const uint16_t* W = wbf + 5*16384;   // out_proj_w bf16
  f32x4 acc[2][4];
#pragma unroll
  for(int a=0;a<2;a++) for(int b=0;b<4;b++) acc[a][b]=z4;
#pragma unroll
  for(int ks=0;ks<4;ks++){
    bf16x8 af[2];
#pragma unroll
    for(int tm=0;tm<2;tm++){
      const int row = wm*32 + tm*16 + l15;
      const int byte = row*256 + ((ks*64 + lh*16) ^ ((row&7)<<4));
      af[tm] = *(const bf16x8*)((const char*)sT2 + byte);
    }
#pragma unroll
    for(int tn=0;tn<4;tn++){
      const int o = wn*64 + tn*16 + l15;
      const bf16x8 bv = *(const bf16x8*)(W + o*128 + ks*32 + lh*8);
#pragma unroll
      for(int tm=0;tm<2;tm++)
        acc[tm][tn] = __builtin_amdgcn_mfma_f32_16x16x32_bf16(af[tm], bv, acc[tm][tn], 0,0,0);
    }
  }
#pragma unroll
  for(int tm=0;tm<2;tm++){
#pragma unroll
    for(int tn=0;tn<4;tn++){
      const int col = wn*64 + tn*16 + l15;
      const float obv = opb[col];
#pragma unroll
      for(int r=0;r<4;r++){
        const int row = wm*32 + tm*16 + lh*4 + r;
        const size_t p = (size_t)(pbase + row);
        const int gbyte = row*256 + ((col*2) ^ ((row&7)<<4));
        const float gv = bf2f(*(const uint16_t*)((const char*)sG + gbyte));
        out[p*128 + col] = (acc[tm][tn][r] + obv) * gv;
      }
    }
  }
}

// ---------------- launch ----------------
extern "C" void kernel_launch(void* const* d_in, const int* in_sizes, int n_in,
                              void* d_out, int out_size, void* d_ws, size_t ws_size,
                              hipStream_t stream)
{
  (void)in_sizes; (void)n_in; (void)out_size; (void)ws_size;
  const float* act   = (const float*)d_in[0];
  const float* mask  = (const float*)d_in[1];
  const float* lnw   = (const float*)d_in[2];
  const float* lnb   = (const float*)d_in[3];
  const float* lpw   = (const float*)d_in[4];
  const float* lpb   = (const float*)d_in[5];
  const float* rpw   = (const float*)d_in[6];
  const float* rpb   = (const float*)d_in[7];
  const float* lgw   = (const float*)d_in[8];
  const float* lgb   = (const float*)d_in[9];
  const float* rgw   = (const float*)d_in[10];
  const float* rgb   = (const float*)d_in[11];
  const float* lncw  = (const float*)d_in[12];
  const float* lncb  = (const float*)d_in[13];
  const float* opw   = (const float*)d_in[14];
  const float* opb   = (const float*)d_in[15];
  const float* gw    = (const float*)d_in[16];
  const float* gb    = (const float*)d_in[17];

  char* ws = (char*)d_ws;
  uint16_t* leftT  = (uint16_t*)(ws);                      // 64MB [C][N*N] bf16
  uint16_t* rightT = (uint16_t*)(ws + ((size_t)64<<20));   // 64MB
  uint16_t* gbuf   = (uint16_t*)(ws + ((size_t)128<<20));  // 64MB [C][N*N] bf16 (c-major)
  uint16_t* tbuf   = (uint16_t*)(ws + ((size_t)192<<20));  // 64MB [C][N*N] bf16
  uint16_t* wbf    = (uint16_t*)(ws + ((size_t)256<<20));  // 192KB: 6 bf16 weight mats

  wconv_k<<<384, 256, 0, stream>>>(lpw, lgw, rpw, rgw, gw, opw, wbf);
  k1_proj<<<4096, 256, 0, stream>>>(act, mask, lnw, lnb, lpb, lgb, rpb, rgb, gb,
                                    wbf, leftT, rightT, gbuf);
  k2_tri<<<2048, 256, 0, stream>>>(leftT, rightT, tbuf);
  k3_out<<<4096, 256, 0, stream>>>(tbuf, gbuf, lncw, lncb, wbf, opb, (float*)d_out);
}

// Round 4
// 344.191 us; speedup vs baseline: 1.5877x; 1.5877x over previous
//
#include <hip/hip_runtime.h>
#include <cstdint>
#include <cstddef>

#define LN_EPS 1e-5f

typedef short bf16x8 __attribute__((ext_vector_type(8)));
typedef float f32x4 __attribute__((ext_vector_type(4)));

__device__ __forceinline__ uint16_t f2bf(float f){
  uint32_t u = __float_as_uint(f);
  u += 0x7fffu + ((u >> 16) & 1u);
  return (uint16_t)(u >> 16);
}
__device__ __forceinline__ float bf2f(uint16_t h){
  return __uint_as_float(((uint32_t)h) << 16);
}
__device__ __forceinline__ float sigm(float x){
  return __builtin_amdgcn_rcpf(1.0f + __expf(-x));
}

// ---------------- K0: convert 6 weight matrices (128x128 fp32) to bf16 ----------------
// order: 0=left_proj_w 1=left_gate_w 2=right_proj_w 3=right_gate_w 4=gating_w 5=out_proj_w
__global__ __launch_bounds__(256) void wconv_k(
    const float* __restrict__ w0, const float* __restrict__ w1,
    const float* __restrict__ w2, const float* __restrict__ w3,
    const float* __restrict__ w4, const float* __restrict__ w5,
    uint16_t* __restrict__ dst)
{
  int i = blockIdx.x*256 + threadIdx.x;   // 6*16384 total
  int m = i >> 14, e = i & 16383;
  const float* s = (m==0)?w0:(m==1)?w1:(m==2)?w2:(m==3)?w3:(m==4)?w4:w5;
  dst[i] = f2bf(s[e]);
}

// ---------------- K1: LN + 5 projections, wave-specialized, W-in-registers ----------------
// 1024 blocks x 768 threads (12 waves); block owns 256 rows, processed as 4 tiles of 64.
// Waves 0-3: left proj+gate (32 cols each); 4-7: right; 8-11: gating + LN of next tile.
// W slices persistent in VGPRs (loaded once); A streamed via double-buffered LDS.
// outputs: leftT/rightT/gbuf c-major [C][N*N] bf16 via double-buffered transpose LDS.
__global__ __launch_bounds__(768, 3) void k1_proj(
    const float* __restrict__ act, const float* __restrict__ mask,
    const float* __restrict__ lnw, const float* __restrict__ lnb,
    const float* __restrict__ lpb, const float* __restrict__ lgB,
    const float* __restrict__ rpb, const float* __restrict__ rgB,
    const float* __restrict__ gB,
    const uint16_t* __restrict__ wbf,
    uint16_t* __restrict__ leftT, uint16_t* __restrict__ rightT,
    uint16_t* __restrict__ gbuf)
{
  __shared__ uint16_t sA[2][64*128];      // 32KB, [row64][c128] bf16 swizzled
  __shared__ uint16_t sT[2][3][128*64];   // 96KB, [c128][p64] bf16 swizzled
  __shared__ float sMask[2][64];
  const int t = threadIdx.x;
  const int lane = t & 63, wid = t >> 6;
  const int p0 = blockIdx.x * 256;
  const int l15 = lane & 15, lh = lane >> 4;
  const bool isG = (wid >= 8);
  const int fam = wid >> 2;               // 0=L, 1=R, 2=G
  const int cbase = (wid & 3) * 32;
  const f32x4 z4 = {0.f,0.f,0.f,0.f};

  // ---- persistent W fragments (loaded once) ----
  bf16x8 Wp[2][4], Wg[2][4];
  {
    const int m0 = (fam==0)?0:(fam==1)?2:4;
#pragma unroll
    for(int tn=0;tn<2;tn++){
      const int o = cbase + tn*16 + l15;
#pragma unroll
      for(int ks=0;ks<4;ks++)
        Wp[tn][ks] = *(const bf16x8*)(wbf + m0*16384 + o*128 + ks*32 + lh*8);
    }
    if(!isG){
#pragma unroll
      for(int tn=0;tn<2;tn++){
        const int o = cbase + tn*16 + l15;
#pragma unroll
        for(int ks=0;ks<4;ks++)
          Wg[tn][ks] = *(const bf16x8*)(wbf + (m0+1)*16384 + o*128 + ks*32 + lh*8);
      }
    }
  }
  // ---- biases (persistent scalars) ----
  float pbv[2], gbv[2];
  {
    const float* pb  = (fam==0)? lpb : (fam==1)? rpb : gB;
    const float* gb2 = (fam==0)? lgB : rgB;
#pragma unroll
    for(int tn=0;tn<2;tn++){
      const int c = cbase + tn*16 + l15;
      pbv[tn] = pb[c];
      gbv[tn] = isG ? 0.f : gb2[c];
    }
  }

  float x[32];        // G-wave LN staging (held across gemm)
  float mval = 0.f;

  // ---- G-wave LN helpers (4 threads per row, 64 rows per tile) ----
  auto ln_load = [&](int tile){
    const int g = t - 512, row = g >> 2, q = g & 3;
    const float* src = act + (size_t)(p0 + tile*64 + row)*128 + q*32;
#pragma unroll
    for(int u=0;u<8;u++){
      float4 v = *(const float4*)(src + u*4);
      x[u*4+0]=v.x; x[u*4+1]=v.y; x[u*4+2]=v.z; x[u*4+3]=v.w;
    }
    if(q==0) mval = mask[p0 + tile*64 + row];
  };
  auto ln_finish = [&](int nb){
    const int g = t - 512, row = g >> 2, q = g & 3;
    float s=0.f, s2=0.f;
#pragma unroll
    for(int u=0;u<32;u++){ s += x[u]; s2 += x[u]*x[u]; }
    s  += __shfl_xor(s,1);  s  += __shfl_xor(s,2);
    s2 += __shfl_xor(s2,1); s2 += __shfl_xor(s2,2);
    const float mu   = s * (1.f/128.f);
    const float var  = s2 * (1.f/128.f) - mu*mu;
    const float rstd = rsqrtf(var + LN_EPS);
    const int rs = (row&7)<<4;
#pragma unroll
    for(int u=0;u<4;u++){
      const int c0 = q*32 + u*8;
      float4 w0 = *(const float4*)(lnw + c0), w1 = *(const float4*)(lnw + c0 + 4);
      float4 b0 = *(const float4*)(lnb + c0), b1 = *(const float4*)(lnb + c0 + 4);
      uint16_t h[8];
      h[0]=f2bf((x[u*8+0]-mu)*rstd*w0.x+b0.x); h[1]=f2bf((x[u*8+1]-mu)*rstd*w0.y+b0.y);
      h[2]=f2bf((x[u*8+2]-mu)*rstd*w0.z+b0.z); h[3]=f2bf((x[u*8+3]-mu)*rstd*w0.w+b0.w);
      h[4]=f2bf((x[u*8+4]-mu)*rstd*w1.x+b1.x); h[5]=f2bf((x[u*8+5]-mu)*rstd*w1.y+b1.y);
      h[6]=f2bf((x[u*8+6]-mu)*rstd*w1.z+b1.z); h[7]=f2bf((x[u*8+7]-mu)*rstd*w1.w+b1.w);
      uint4 pk;
      pk.x = (uint32_t)h[0] | ((uint32_t)h[1]<<16);
      pk.y = (uint32_t)h[2] | ((uint32_t)h[3]<<16);
      pk.z = (uint32_t)h[4] | ((uint32_t)h[5]<<16);
      pk.w = (uint32_t)h[6] | ((uint32_t)h[7]<<16);
      *(uint4*)((char*)sA[nb] + row*256 + ((c0*2) ^ rs)) = pk;
    }
    if(q==0) sMask[nb][row] = mval;
  };

  // ---- gemm + fused epilogue for one 64-row tile ----
  auto work = [&](int cb){
    uint16_t* sTf = sT[cb][fam];
#pragma unroll
    for(int rt=0; rt<4; rt++){
      bf16x8 af[4];
      const int arow = rt*16 + l15;
      const int ars = (arow&7)<<4;
#pragma unroll
      for(int ks=0;ks<4;ks++)
        af[ks] = *(const bf16x8*)((const char*)sA[cb] + arow*256 + ((ks*64+lh*16) ^ ars));
      f32x4 aP[2] = {z4,z4}, aQ[2] = {z4,z4};
      if(isG){
#pragma unroll
        for(int ks=0;ks<4;ks++)
#pragma unroll
          for(int tn=0;tn<2;tn++)
            aP[tn] = __builtin_amdgcn_mfma_f32_16x16x32_bf16(af[ks], Wp[tn][ks], aP[tn], 0,0,0);
      } else {
#pragma unroll
        for(int ks=0;ks<4;ks++)
#pragma unroll
          for(int tn=0;tn<2;tn++){
            aP[tn] = __builtin_amdgcn_mfma_f32_16x16x32_bf16(af[ks], Wp[tn][ks], aP[tn], 0,0,0);
            aQ[tn] = __builtin_amdgcn_mfma_f32_16x16x32_bf16(af[ks], Wg[tn][ks], aQ[tn], 0,0,0);
          }
      }
      const int prow = rt*16 + lh*4;
      const int poff = prow*2;
#pragma unroll
      for(int tn=0;tn<2;tn++){
        const int c = cbase + tn*16 + l15;
        uint16_t h[4];
        if(isG){
#pragma unroll
          for(int r=0;r<4;r++)
            h[r] = f2bf(sigm(aP[tn][r] + pbv[tn]));
        } else {
#pragma unroll
          for(int r=0;r<4;r++)
            h[r] = f2bf(sMask[cb][prow+r]*(aP[tn][r]+pbv[tn]) * sigm(aQ[tn][r]+gbv[tn]));
        }
        uint2 pk;
        pk.x = (uint32_t)h[0] | ((uint32_t)h[1]<<16);
        pk.y = (uint32_t)h[2] | ((uint32_t)h[3]<<16);
        *(uint2*)((char*)sTf + c*128 + (poff ^ ((c&7)<<4))) = pk;
      }
    }
  };

  // ---- coalesced c-major readout of one sT buffer (all 768 threads) ----
  auto readout = [&](int sb, int pbase){
    const int oi = t >> 8;                // 0=L,1=R,2=G
    const int c = (t >> 1) & 127;
    const int ph = (t & 1) * 32;
    const int cs = (c&7) << 4;
    const char* src = (const char*)sT[sb][oi];
    uint4 q[4];
#pragma unroll
    for(int u=0;u<4;u++)
      q[u] = *(const uint4*)(src + c*128 + ((ph*2 + u*16) ^ cs));
    uint16_t* base = (oi==0)? leftT : (oi==1)? rightT : gbuf;
    uint16_t* dst = base + (size_t)c*262144 + pbase + ph;
    *(uint4*)(dst+ 0)=q[0]; *(uint4*)(dst+ 8)=q[1];
    *(uint4*)(dst+16)=q[2]; *(uint4*)(dst+24)=q[3];
  };

  // ---- prologue: G waves LN tile 0; others just have W loaded ----
  if(isG){
    ln_load(0);
    ln_finish(0);
  }
  __syncthreads();

  // ---- main loop: 4 tiles, 1 barrier per tile ----
  for(int mt=0; mt<4; mt++){
    const int cb = mt & 1;
    if(isG && mt < 3) ln_load(mt+1);            // issue next act loads early
    if(mt > 0) readout(cb^1, p0 + (mt-1)*64);   // drain previous tile
    work(cb);                                   // gemm + epi -> sT[cb]
    if(isG && mt < 3) ln_finish(cb^1);          // LN next tile -> sA[cb^1]
    __syncthreads();
  }
  readout(1, p0 + 192);                         // tile 3 lives in sT[1]
}

// ---------------- K2: triangle einsum, 128 c-batched 512x512x512 GEMMs ----------------
// t_c[i][j] = sum_k L_c[i][k] * R_c[j][k]; 2048 blocks (XCD-chunk swizzled), tile 128x128, BK=64.
__global__ __launch_bounds__(256) void k2_tri(
    const uint16_t* __restrict__ leftT, const uint16_t* __restrict__ rightT,
    uint16_t* __restrict__ tbuf)
{
  __shared__ uint16_t sm[2*128*64];   // 32KB: sL | sR; reused as [128][128] C-tile in epilogue
  uint16_t* sL = sm;
  uint16_t* sR = sm + 128*64;
  // XCD-chunked bijective swizzle: 2048 = 8 * 256 -> each XCD gets 16 consecutive c-groups
  const int bx = (blockIdx.x & 7)*256 + (blockIdx.x >> 3);
  const int c = bx >> 4, it = (bx >> 2) & 3, jt = bx & 3;
  const uint16_t* L = leftT  + (size_t)c*262144;
  const uint16_t* R = rightT + (size_t)c*262144;
  const int t = threadIdx.x, lane = t & 63, wid = t >> 6;
  const int wm = wid >> 1, wn = wid & 1;   // wave: 64x64 of the 128x128 tile
  const int l15 = lane & 15, lh = lane >> 4;
  const f32x4 z4 = {0.f,0.f,0.f,0.f};
  f32x4 acc[4][4];
#pragma unroll
  for(int a=0;a<4;a++) for(int b=0;b<4;b++) acc[a][b]=z4;

  const int srow = t >> 1, shalf = (t & 1)*64;  // staging: 64B per thread per matrix
  for(int kt=0; kt<8; kt++){
    __syncthreads();
#pragma unroll
    for(int u=0;u<4;u++){
      const int kb = shalf + u*16;                 // byte within the 128B row
      const int ge = kt*64 + (kb >> 1);            // global k element
      const int db = srow*128 + (kb ^ ((srow&7)<<4));
      uint4 va = *(const uint4*)(L + (size_t)(it*128+srow)*512 + ge);
      *(uint4*)((char*)sL + db) = va;
      uint4 vb = *(const uint4*)(R + (size_t)(jt*128+srow)*512 + ge);
      *(uint4*)((char*)sR + db) = vb;
    }
    __syncthreads();
#pragma unroll
    for(int ks=0;ks<2;ks++){
      bf16x8 af[4], bv[4];
#pragma unroll
      for(int tm=0;tm<4;tm++){
        const int row = wm*64 + tm*16 + l15;
        const int byte = row*128 + ((ks*64 + lh*16) ^ ((row&7)<<4));
        af[tm] = *(const bf16x8*)((const char*)sL + byte);
      }
#pragma unroll
      for(int tn=0;tn<4;tn++){
        const int row = wn*64 + tn*16 + l15;
        const int byte = row*128 + ((ks*64 + lh*16) ^ ((row&7)<<4));
        bv[tn] = *(const bf16x8*)((const char*)sR + byte);
      }
#pragma unroll
      for(int tm=0;tm<4;tm++)
#pragma unroll
        for(int tn=0;tn<4;tn++)
          acc[tm][tn] = __builtin_amdgcn_mfma_f32_16x16x32_bf16(af[tm], bv[tn], acc[tm][tn], 0,0,0);
    }
  }
  // epilogue: scatter into LDS [i][j] tile, then coalesced 128B-contiguous stores
  __syncthreads();
#pragma unroll
  for(int tm=0;tm<4;tm++){
#pragma unroll
    for(int tn=0;tn<4;tn++){
      const int j = wn*64 + tn*16 + l15;
#pragma unroll
      for(int r=0;r<4;r++){
        const int i = wm*64 + tm*16 + lh*4 + r;
        const int byte = i*256 + ((j*2) ^ ((i&7)<<4));
        *(uint16_t*)((char*)sm + byte) = f2bf(acc[tm][tn][r]);
      }
    }
  }
  __syncthreads();
  {
    const int i = t >> 1, half = (t & 1)*64;
    uint16_t* dst = tbuf + (size_t)c*262144 + (size_t)(it*128+i)*512 + jt*128 + half;
#pragma unroll
    for(int u=0;u<8;u++){
      const int byte = i*256 + ((half*2 + u*16) ^ ((i&7)<<4));
      *(uint4*)(dst + u*8) = *(const uint4*)((const char*)sm + byte);
    }
  }
}

// ---------------- K3: LN_c + out_proj + gating multiply ----------------
// grid 4096: block owns positions (i, j0..j0+63); reads t and g (both c-major), writes fp32 out.
__global__ __launch_bounds__(256) void k3_out(
    const uint16_t* __restrict__ tbuf, const uint16_t* __restrict__ gbuf,
    const float* __restrict__ lncw, const float* __restrict__ lncb,
    const uint16_t* __restrict__ wbf, const float* __restrict__ opb,
    float* __restrict__ out)
{
  __shared__ uint16_t sT2[64*128];  // 16KB [p 64][c 128] bf16, swizzled
  __shared__ uint16_t sG[64*128];   // 16KB [p 64][c 128] bf16, swizzled
  const int bx = blockIdx.x;
  const int i = bx >> 3, j0 = (bx & 7)*64;
  const int t = threadIdx.x;
  const int pbase = i*512 + j0;

  { // transpose-load t and g: thread -> (c = t>>1, 32 consecutive j)
    const int c = t >> 1, ph = (t & 1)*32;
    const uint16_t* srcT = tbuf + (size_t)c*262144 + pbase + ph;
    const uint16_t* srcG = gbuf + (size_t)c*262144 + pbase + ph;
#pragma unroll
    for(int u=0;u<4;u++){
      uint4 v = *(const uint4*)(srcT + u*8);
      uint4 g = *(const uint4*)(srcG + u*8);
      uint16_t et[8], eg[8];
      et[0]=(uint16_t)(v.x&0xffff); et[1]=(uint16_t)(v.x>>16);
      et[2]=(uint16_t)(v.y&0xffff); et[3]=(uint16_t)(v.y>>16);
      et[4]=(uint16_t)(v.z&0xffff); et[5]=(uint16_t)(v.z>>16);
      et[6]=(uint16_t)(v.w&0xffff); et[7]=(uint16_t)(v.w>>16);
      eg[0]=(uint16_t)(g.x&0xffff); eg[1]=(uint16_t)(g.x>>16);
      eg[2]=(uint16_t)(g.y&0xffff); eg[3]=(uint16_t)(g.y>>16);
      eg[4]=(uint16_t)(g.z&0xffff); eg[5]=(uint16_t)(g.z>>16);
      eg[6]=(uint16_t)(g.w&0xffff); eg[7]=(uint16_t)(g.w>>16);
#pragma unroll
      for(int k2=0;k2<8;k2++){
        const int p = ph + u*8 + k2;
        const int byte = p*256 + ((c*2) ^ ((p&7)<<4));
        *(uint16_t*)((char*)sT2 + byte) = et[k2];
        *(uint16_t*)((char*)sG + byte) = eg[k2];
      }
    }
  }
  __syncthreads();

  const int lane = t & 63, wid = t >> 6;
  { // LayerNorm over c per position row (fp32), 4 lanes per row
    const int row = wid*16 + (lane & 15);
    const int q = lane >> 4;
    float xs[32];
#pragma unroll
    for(int u=0;u<4;u++){
      const int kb = q*64 + u*16;
      const int byte = row*256 + (kb ^ ((row&7)<<4));
      uint4 v = *(const uint4*)((const char*)sT2 + byte);
      xs[u*8+0]=bf2f((uint16_t)(v.x&0xffff)); xs[u*8+1]=bf2f((uint16_t)(v.x>>16));
      xs[u*8+2]=bf2f((uint16_t)(v.y&0xffff)); xs[u*8+3]=bf2f((uint16_t)(v.y>>16));
      xs[u*8+4]=bf2f((uint16_t)(v.z&0xffff)); xs[u*8+5]=bf2f((uint16_t)(v.z>>16));
      xs[u*8+6]=bf2f((uint16_t)(v.w&0xffff)); xs[u*8+7]=bf2f((uint16_t)(v.w>>16));
    }
    float s=0.f, s2=0.f;
#pragma unroll
    for(int u=0;u<32;u++){ s += xs[u]; s2 += xs[u]*xs[u]; }
    s  += __shfl_xor(s,16);  s  += __shfl_xor(s,32);
    s2 += __shfl_xor(s2,16); s2 += __shfl_xor(s2,32);
    const float mu   = s * (1.f/128.f);
    const float var  = s2 * (1.f/128.f) - mu*mu;
    const float rstd = rsqrtf(var + LN_EPS);
#pragma unroll
    for(int u=0;u<4;u++){
      const int kb = q*64 + u*16;
      const int c0 = (kb ^ ((row&7)<<4)) >> 1;    // de-swizzled channel of this 16B block
      uint16_t h[8];
#pragma unroll
      for(int j=0;j<8;j++)
        h[j] = f2bf((xs[u*8+j]-mu)*rstd*lncw[c0+j] + lncb[c0+j]);
      uint4 pk;
      pk.x = (uint32_t)h[0] | ((uint32_t)h[1]<<16);
      pk.y = (uint32_t)h[2] | ((uint32_t)h[3]<<16);
      pk.z = (uint32_t)h[4] | ((uint32_t)h[5]<<16);
      pk.w = (uint32_t)h[6] | ((uint32_t)h[7]<<16);
      const int byte = row*256 + (kb ^ ((row&7)<<4));
      *(uint4*)((char*)sT2 + byte) = pk;
    }
  }
  __syncthreads();

  const int wm = wid >> 1, wn = wid & 1;
  const int l15 = lane & 15, lh = lane >> 4;
  const f32x4 z4 = {0.f,0.f,0.f,0.f};
  const uint16_t* W = wbf + 5*16384;   // out_proj_w bf16
  f32x4 acc[2][4];
#pragma unroll
  for(int a=0;a<2;a++) for(int b=0;b<4;b++) acc[a][b]=z4;
#pragma unroll
  for(int ks=0;ks<4;ks++){
    bf16x8 af[2];
#pragma unroll
    for(int tm=0;tm<2;tm++){
      const int row = wm*32 + tm*16 + l15;
      const int byte = row*256 + ((ks*64 + lh*16) ^ ((row&7)<<4));
      af[tm] = *(const bf16x8*)((const char*)sT2 + byte);
    }
#pragma unroll
    for(int tn=0;tn<4;tn++){
      const int o = wn*64 + tn*16 + l15;
      const bf16x8 bv = *(const bf16x8*)(W + o*128 + ks*32 + lh*8);
#pragma unroll
      for(int tm=0;tm<2;tm++)
        acc[tm][tn] = __builtin_amdgcn_mfma_f32_16x16x32_bf16(af[tm], bv, acc[tm][tn], 0,0,0);
    }
  }
#pragma unroll
  for(int tm=0;tm<2;tm++){
#pragma unroll
    for(int tn=0;tn<4;tn++){
      const int col = wn*64 + tn*16 + l15;
      const float obv = opb[col];
#pragma unroll
      for(int r=0;r<4;r++){
        const int row = wm*32 + tm*16 + lh*4 + r;
        const size_t p = (size_t)(pbase + row);
        const int gbyte = row*256 + ((col*2) ^ ((row&7)<<4));
        const float gv = bf2f(*(const uint16_t*)((const char*)sG + gbyte));
        out[p*128 + col] = (acc[tm][tn][r] + obv) * gv;
      }
    }
  }
}

// ---------------- launch ----------------
extern "C" void kernel_launch(void* const* d_in, const int* in_sizes, int n_in,
                              void* d_out, int out_size, void* d_ws, size_t ws_size,
                              hipStream_t stream)
{
  (void)in_sizes; (void)n_in; (void)out_size; (void)ws_size;
  const float* act   = (const float*)d_in[0];
  const float* mask  = (const float*)d_in[1];
  const float* lnw   = (const float*)d_in[2];
  const float* lnb   = (const float*)d_in[3];
  const float* lpw   = (const float*)d_in[4];
  const float* lpb   = (const float*)d_in[5];
  const float* rpw   = (const float*)d_in[6];
  const float* rpb   = (const float*)d_in[7];
  const float* lgw   = (const float*)d_in[8];
  const float* lgb   = (const float*)d_in[9];
  const float* rgw   = (const float*)d_in[10];
  const float* rgb   = (const float*)d_in[11];
  const float* lncw  = (const float*)d_in[12];
  const float* lncb  = (const float*)d_in[13];
  const float* opw   = (const float*)d_in[14];
  const float* opb   = (const float*)d_in[15];
  const float* gw    = (const float*)d_in[16];
  const float* gb    = (const float*)d_in[17];

  char* ws = (char*)d_ws;
  uint16_t* leftT  = (uint16_t*)(ws);                      // 64MB [C][N*N] bf16
  uint16_t* rightT = (uint16_t*)(ws + ((size_t)64<<20));   // 64MB
  uint16_t* gbuf   = (uint16_t*)(ws + ((size_t)128<<20));  // 64MB [C][N*N] bf16 (c-major)
  uint16_t* tbuf   = (uint16_t*)(ws + ((size_t)192<<20));  // 64MB [C][N*N] bf16
  uint16_t* wbf    = (uint16_t*)(ws + ((size_t)256<<20));  // 192KB: 6 bf16 weight mats

  wconv_k<<<384, 256, 0, stream>>>(lpw, lgw, rpw, rgw, gw, opw, wbf);
  k1_proj<<<1024, 768, 0, stream>>>(act, mask, lnw, lnb, lpb, lgb, rpb, rgb, gb,
                                    wbf, leftT, rightT, gbuf);
  k2_tri<<<2048, 256, 0, stream>>>(leftT, rightT, tbuf);
  k3_out<<<4096, 256, 0, stream>>>(tbuf, gbuf, lncw, lncb, wbf, opb, (float*)d_out);
}